// Round 16
// baseline (49.620 us; speedup 1.0000x reference)
//
#include <hip/hip_runtime.h>
#include <hip/hip_bf16.h>
#include <math.h>

#define CCH   256      // IN_CHANNELS
#define HH    128
#define WW    128
#define EPSF  1e-12f
#define EPS81 8.1e-11f // 81 * 1e-12
#define SLOPE 0.2f

// ws: pooled[3*N*512] | h1[3*N*256] | h2[3*N*256] | h3[3*N*128] | cnt[8]
// cnt[0]: L1-done (192), cnt[1]: L2-done (192), cnt[2]: L3-done (96).
// cnt zeroed by stats (agent-scope atomic stores -> MALL-visible, stream-ordered).

// ---- fence-free cross-XCD helpers: write-through/bypass at coherence point ----
__device__ __forceinline__ void astore(float* p, float v) {
    __hip_atomic_store(p, v, __ATOMIC_RELAXED, __HIP_MEMORY_SCOPE_AGENT);
}
__device__ __forceinline__ float aload(const float* p) {
    return __hip_atomic_load(const_cast<float*>(p), __ATOMIC_RELAXED,
                             __HIP_MEMORY_SCOPE_AGENT);
}
__device__ __forceinline__ void signal(int* c) {
    __syncthreads();   // drains each wave's vmcnt before barrier (guide §5): all
                       // write-through stores are at MALL when any lane proceeds
    if (threadIdx.x == 0)
        __hip_atomic_fetch_add(c, 1, __ATOMIC_RELAXED, __HIP_MEMORY_SCOPE_AGENT);
}
__device__ __forceinline__ void spin_on(int* c, int target) {
    if (threadIdx.x == 0) {
        while (__hip_atomic_load(c, __ATOMIC_RELAXED, __HIP_MEMORY_SCOPE_AGENT) < target)
            __builtin_amdgcn_s_sleep(2);
    }
    __syncthreads();
}
__device__ __forceinline__ void keep4(float4 v) {
    asm volatile("" :: "v"(v.x), "v"(v.y), "v"(v.z), "v"(v.w));
}

__device__ __forceinline__ void k3_loadrow(const float* __restrict__ plane, int r, int jb,
                                           float4& rs, float4& rq) {
    const float* rp = &plane[r * WW + jb];
    float4 v = *reinterpret_cast<const float4*>(rp);
    float2 w = *reinterpret_cast<const float2*>(rp + 4);
    float t12 = v.y + v.z, t34 = v.w + w.x;
    rs.x = v.x + t12; rs.y = t12 + v.w; rs.z = v.z + t34; rs.w = t34 + w.y;
    float y0 = v.x * v.x, y1 = v.y * v.y, y2 = v.z * v.z;
    float y3 = v.w * v.w, y4 = w.x * w.x, y5 = w.y * w.y;
    float u12 = y1 + y2, u34 = y3 + y4;
    rq.x = y0 + u12; rq.y = u12 + y3; rq.z = y2 + u34; rq.w = u34 + y5;
}

__device__ __forceinline__ void win_acc(float S, float Q, float wm, float& aS, float& aD) {
    float d = fmaxf(fmaf(S, -S, 9.f * Q), 0.f);
    aS = fmaf(wm, S, aS);
    aD = fmaf(wm, sqrtf(d + EPS81), aD);
}

__global__ __launch_bounds__(512, 4) void stats_kernel(const float* __restrict__ feat,
                                                       float* __restrict__ pooled,
                                                       int* __restrict__ cnt,
                                                       int N) {
    __shared__ float plane[HH * WW + 8];
    __shared__ float wp[8][6];

    const int p    = blockIdx.x;              // n*C + c
    const int n    = p >> 8;
    const int c    = p & 255;
    const int tid  = threadIdx.x;
    const int wave = tid >> 6, lane = tid & 63;

    // zero consumer counters at the coherence point (MALL) — stream-ordered
    if (p == 0 && tid < 4)
        __hip_atomic_store(&cnt[tid], 0, __ATOMIC_RELAXED, __HIP_MEMORY_SCOPE_AGENT);

    {
        const float* gbase = feat + (size_t)p * (HH * WW) + (tid << 2);
        #pragma unroll
        for (int i = 0; i < 8; ++i) {
            __builtin_amdgcn_global_load_lds(
                (const __attribute__((address_space(1))) void*)(gbase + i * 2048),
                (__attribute__((address_space(3))) void*)&plane[i * 2048 + (wave << 8)],
                16, 0, 0);
        }
        if (tid < 8) plane[HH * WW + tid] = 0.f;
    }
    __syncthreads();

    // =============== K = 3, stride 1, out 126x126 ===============
    float a3S = 0.f, a3D = 0.f;
    {
        const int s  = tid & 31;
        const int g  = tid >> 5;
        const int jb = s << 2;
        const float wm2 = (s < 31) ? 1.f : 0.f;
        const int i0 = g << 3;
        float4 r0s, r0q, r1s, r1q;
        k3_loadrow(plane, i0,     jb, r0s, r0q);
        k3_loadrow(plane, i0 + 1, jb, r1s, r1q);
        #pragma unroll
        for (int t = 0; t < 8; ++t) {
            const int i  = i0 + t;
            const int r2 = (i + 2 < 128) ? (i + 2) : 127;
            float4 r2s, r2q;
            k3_loadrow(plane, r2, jb, r2s, r2q);
            const float wr  = (i < 126) ? 1.f : 0.f;
            const float wrm = wr * wm2;
            float Sx = r0s.x + r1s.x + r2s.x, Qx = r0q.x + r1q.x + r2q.x;
            float Sy = r0s.y + r1s.y + r2s.y, Qy = r0q.y + r1q.y + r2q.y;
            float Sz = r0s.z + r1s.z + r2s.z, Qz = r0q.z + r1q.z + r2q.z;
            float Sw = r0s.w + r1s.w + r2s.w, Qw = r0q.w + r1q.w + r2q.w;
            win_acc(Sx, Qx, wr,  a3S, a3D);
            win_acc(Sy, Qy, wr,  a3S, a3D);
            win_acc(Sz, Qz, wrm, a3S, a3D);
            win_acc(Sw, Qw, wrm, a3S, a3D);
            r0s = r1s; r0q = r1q; r1s = r2s; r1q = r2q;
        }
    }

    // =============== K = 34, stride 16, out 6x6 ===============
    float am34 = 0.f, as34 = 0.f;
    for (int w = wave; w < 36; w += 8) {
        int wi = w / 6, wj = w - 6 * wi;
        int r0 = wi << 4, c0 = wj << 4;
        float S = 0.f, Q = 0.f;
        #pragma unroll
        for (int it = 0; it < 5; ++it) {
            int t = lane + (it << 6);
            if (t < 306) {
                int r = t / 9, c4 = t - 9 * r;
                const float* rp = &plane[(r0 + r) * WW + c0 + (c4 << 2)];
                float4 v = *reinterpret_cast<const float4*>(rp);
                if (c4 == 8) { v.z = 0.f; v.w = 0.f; }
                S += (v.x + v.y) + (v.z + v.w);
                Q = fmaf(v.x, v.x, Q); Q = fmaf(v.y, v.y, Q);
                Q = fmaf(v.z, v.z, Q); Q = fmaf(v.w, v.w, Q);
            }
        }
        #pragma unroll
        for (int off = 32; off > 0; off >>= 1) {
            S += __shfl_down(S, off);
            Q += __shfl_down(Q, off);
        }
        if (lane == 0) {
            const float inv = 1.f / 1156.f;
            float mean = S * inv;
            float var  = fmaxf(fmaf(-mean, mean, Q * inv), 0.f);
            am34 += mean;
            as34 += sqrtf(var + EPSF);
        }
    }

    // =============== K = 65, stride 32, out 2x2 ===============
    float m65 = 0.f, s65 = 0.f;
    if (wave >= 4) {
        int w  = wave - 4;
        int wi = w >> 1, wj = w & 1;
        int r0 = wi << 5, c0 = wj << 5;
        float S = 0.f, Q = 0.f;
        #pragma unroll
        for (int it = 0; it < 18; ++it) {
            int t = lane + (it << 6);
            if (t < 1105) {
                int r = t / 17, c4 = t - 17 * r;
                const float* rp = &plane[(r0 + r) * WW + c0 + (c4 << 2)];
                float4 v = *reinterpret_cast<const float4*>(rp);
                if (c4 == 16) { v.y = 0.f; v.z = 0.f; v.w = 0.f; }
                S += (v.x + v.y) + (v.z + v.w);
                Q = fmaf(v.x, v.x, Q); Q = fmaf(v.y, v.y, Q);
                Q = fmaf(v.z, v.z, Q); Q = fmaf(v.w, v.w, Q);
            }
        }
        #pragma unroll
        for (int off = 32; off > 0; off >>= 1) {
            S += __shfl_down(S, off);
            Q += __shfl_down(Q, off);
        }
        if (lane == 0) {
            const float inv = 1.f / 4225.f;
            float mean = S * inv;
            float var  = fmaxf(fmaf(-mean, mean, Q * inv), 0.f);
            m65 = mean;
            s65 = sqrtf(var + EPSF);
        }
    }

    #pragma unroll
    for (int off = 32; off > 0; off >>= 1) {
        a3S += __shfl_down(a3S, off);
        a3D += __shfl_down(a3D, off);
    }
    if (lane == 0) {
        wp[wave][0] = a3S; wp[wave][1] = a3D;
        wp[wave][2] = am34; wp[wave][3] = as34;
        wp[wave][4] = m65;  wp[wave][5] = s65;
    }
    __syncthreads();
    if (tid == 0) {
        float A3 = 0.f, D3 = 0.f, M34 = 0.f, S34 = 0.f, M65 = 0.f, S65 = 0.f;
        #pragma unroll
        for (int w = 0; w < 8; ++w) {
            A3 += wp[w][0]; D3 += wp[w][1];
            M34 += wp[w][2]; S34 += wp[w][3];
            M65 += wp[w][4]; S65 += wp[w][5];
        }
        const float inv3 = 1.f / (9.f * 126.f * 126.f);
        pooled[(0 * N + n) * 512 + c]       = A3 * inv3;
        pooled[(0 * N + n) * 512 + 256 + c] = D3 * inv3;
        pooled[(1 * N + n) * 512 + c]       = M34 * (1.f / 36.f);
        pooled[(1 * N + n) * 512 + 256 + c] = S34 * (1.f / 36.f);
        pooled[(2 * N + n) * 512 + c]       = M65 * 0.25f;
        pooled[(2 * N + n) * 512 + 256 + c] = S65 * 0.25f;
    }
}

__device__ __forceinline__ float leaky(float v) { return v > 0.f ? v : SLOPE * v; }

// ONE MLP node, 481 blocks x 256 threads, role-split:
//  blocks [0,192)   : L1 (512->256), one wave per (k,o); signals cnt[0]
//  blocks [192,384) : L2 (256->256), prefetch weights, spin cnt[0]==192
//  blocks [384,480) : L3 (256->128), prefetch weights, spin cnt[1]==192
//  block  480       : L4+loss+total, spin cnt[2]==96
// Co-resident by capacity (481 << 1024 slots at 4 blocks/CU) -> spins deadlock-free.
__global__ __launch_bounds__(256, 4) void mlp_mega(const float* __restrict__ pooled,
                                                   const float* __restrict__ W1, const float* __restrict__ b1,
                                                   const float* __restrict__ W2, const float* __restrict__ b2,
                                                   const float* __restrict__ W3, const float* __restrict__ b3,
                                                   const float* __restrict__ W4, const float* __restrict__ b4,
                                                   const int* __restrict__ label,
                                                   float* __restrict__ h1,
                                                   float* __restrict__ h2,
                                                   float* __restrict__ h3,
                                                   int* __restrict__ cnt,
                                                   float* __restrict__ out) {
    __shared__ float lossArr[6];
    const int blk  = blockIdx.x;
    const int tid  = threadIdx.x;
    const int wave = tid >> 6, lane = tid & 63;

    if (blk < 192) {
        // ---------------- L1: 512 -> 256 ----------------
        const int r = blk * 4 + wave;          // 0..767
        const int k = r >> 8, o = r & 255;
        const float4* w4  = reinterpret_cast<const float4*>(W1 + ((size_t)k * 256 + o) * 512);
        const float4* x04 = reinterpret_cast<const float4*>(pooled + (size_t)(k * 2 + 0) * 512);
        const float4* x14 = reinterpret_cast<const float4*>(pooled + (size_t)(k * 2 + 1) * 512);
        float4 wa = w4[lane], wb = w4[lane + 64];
        float4 xa = x04[lane], xb = x04[lane + 64];
        float4 ya = x14[lane], yb = x14[lane + 64];
        float bb = b1[(size_t)k * 256 + o];
        float s0 = 0.f, s1 = 0.f;
        s0 = fmaf(wa.x, xa.x, s0); s0 = fmaf(wa.y, xa.y, s0);
        s0 = fmaf(wa.z, xa.z, s0); s0 = fmaf(wa.w, xa.w, s0);
        s1 = fmaf(wa.x, ya.x, s1); s1 = fmaf(wa.y, ya.y, s1);
        s1 = fmaf(wa.z, ya.z, s1); s1 = fmaf(wa.w, ya.w, s1);
        s0 = fmaf(wb.x, xb.x, s0); s0 = fmaf(wb.y, xb.y, s0);
        s0 = fmaf(wb.z, xb.z, s0); s0 = fmaf(wb.w, xb.w, s0);
        s1 = fmaf(wb.x, yb.x, s1); s1 = fmaf(wb.y, yb.y, s1);
        s1 = fmaf(wb.z, yb.z, s1); s1 = fmaf(wb.w, yb.w, s1);
        #pragma unroll
        for (int off = 32; off > 0; off >>= 1) {
            s0 += __shfl_down(s0, off);
            s1 += __shfl_down(s1, off);
        }
        if (lane == 0) {
            astore(&h1[(size_t)(k * 2 + 0) * 256 + o], leaky(s0 + bb));
            astore(&h1[(size_t)(k * 2 + 1) * 256 + o], leaky(s1 + bb));
        }
        signal(&cnt[0]);
    } else if (blk < 384) {
        // ---------------- L2: 256 -> 256 ----------------
        const int r = (blk - 192) * 4 + wave;  // 0..767
        const int k = r >> 8, o = r & 255;
        const float4* w4 = reinterpret_cast<const float4*>(W2 + ((size_t)k * 256 + o) * 256);
        float4 wv = w4[lane];                   // prefetch: overlaps L1
        float bb = b2[(size_t)k * 256 + o];
        keep4(wv); asm volatile("" :: "v"(bb));

        spin_on(&cnt[0], 192);

        const float* x0 = h1 + (size_t)(k * 2 + 0) * 256 + (lane << 2);
        const float* x1 = h1 + (size_t)(k * 2 + 1) * 256 + (lane << 2);
        float a0 = aload(x0), a1 = aload(x0 + 1), a2 = aload(x0 + 2), a3 = aload(x0 + 3);
        float d0 = aload(x1), d1 = aload(x1 + 1), d2 = aload(x1 + 2), d3 = aload(x1 + 3);
        float s0 = 0.f, s1 = 0.f;
        s0 = fmaf(wv.x, a0, s0); s0 = fmaf(wv.y, a1, s0);
        s0 = fmaf(wv.z, a2, s0); s0 = fmaf(wv.w, a3, s0);
        s1 = fmaf(wv.x, d0, s1); s1 = fmaf(wv.y, d1, s1);
        s1 = fmaf(wv.z, d2, s1); s1 = fmaf(wv.w, d3, s1);
        #pragma unroll
        for (int off = 32; off > 0; off >>= 1) {
            s0 += __shfl_down(s0, off);
            s1 += __shfl_down(s1, off);
        }
        if (lane == 0) {
            astore(&h2[(size_t)(k * 2 + 0) * 256 + o], leaky(s0 + bb));
            astore(&h2[(size_t)(k * 2 + 1) * 256 + o], leaky(s1 + bb));
        }
        signal(&cnt[1]);
    } else if (blk < 480) {
        // ---------------- L3: 256 -> 128 ----------------
        const int r = (blk - 384) * 4 + wave;  // 0..383
        const int k = r >> 7, o = r & 127;
        const float4* w4 = reinterpret_cast<const float4*>(W3 + ((size_t)k * 128 + o) * 256);
        float4 wv = w4[lane];                   // prefetch
        float bb = b3[(size_t)k * 128 + o];
        keep4(wv); asm volatile("" :: "v"(bb));

        spin_on(&cnt[1], 192);

        const float* x0 = h2 + (size_t)(k * 2 + 0) * 256 + (lane << 2);
        const float* x1 = h2 + (size_t)(k * 2 + 1) * 256 + (lane << 2);
        float a0 = aload(x0), a1 = aload(x0 + 1), a2 = aload(x0 + 2), a3 = aload(x0 + 3);
        float d0 = aload(x1), d1 = aload(x1 + 1), d2 = aload(x1 + 2), d3 = aload(x1 + 3);
        float s0 = 0.f, s1 = 0.f;
        s0 = fmaf(wv.x, a0, s0); s0 = fmaf(wv.y, a1, s0);
        s0 = fmaf(wv.z, a2, s0); s0 = fmaf(wv.w, a3, s0);
        s1 = fmaf(wv.x, d0, s1); s1 = fmaf(wv.y, d1, s1);
        s1 = fmaf(wv.z, d2, s1); s1 = fmaf(wv.w, d3, s1);
        #pragma unroll
        for (int off = 32; off > 0; off >>= 1) {
            s0 += __shfl_down(s0, off);
            s1 += __shfl_down(s1, off);
        }
        if (lane == 0) {
            astore(&h3[(size_t)(k * 2 + 0) * 128 + o], leaky(s0 + bb));
            astore(&h3[(size_t)(k * 2 + 1) * 128 + o], leaky(s1 + bb));
        }
        signal(&cnt[2]);
    } else {
        // ---------------- L4 + loss + total (block 480) ----------------
        // prefetch first pair's weights while L1/L2/L3 run
        const int k0 = wave >> 1;
        float w0 = W4[(size_t)k0 * 128 + lane], w1 = W4[(size_t)k0 * 128 + 64 + lane];
        float bb0 = b4[k0];
        float y = (float)(*label);
        asm volatile("" :: "v"(w0), "v"(w1), "v"(bb0), "v"(y));

        spin_on(&cnt[2], 96);

        #pragma unroll
        for (int pr = 0; pr < 2; ++pr) {
            const int pair = wave + pr * 4;    // 0..5 (waves 0..3, then 0..1)
            if (pair < 6) {
                const int k = pair >> 1;
                float ww0 = (pr == 0) ? w0 : W4[(size_t)k * 128 + lane];
                float ww1 = (pr == 0) ? w1 : W4[(size_t)k * 128 + 64 + lane];
                float bbk = (pr == 0) ? bb0 : b4[k];
                const float* x = h3 + (size_t)pair * 128;
                float s = ww0 * aload(x + lane) + ww1 * aload(x + 64 + lane);
                #pragma unroll
                for (int off = 32; off > 0; off >>= 1) s += __shfl_down(s, off);
                if (lane == 0) {
                    float logit = s + bbk;
                    float sp = fmaxf(logit, 0.f) + log1pf(expf(-fabsf(logit)));
                    lossArr[pair] = sp - logit * y;
                }
            }
        }
        __syncthreads();
        if (tid == 0) {
            float tot = 0.f;
            #pragma unroll
            for (int kk = 0; kk < 3; ++kk)
                tot += (lossArr[kk * 2 + 0] + lossArr[kk * 2 + 1]) * 0.5f;
            out[0] = tot;
        }
    }
}

extern "C" void kernel_launch(void* const* d_in, const int* in_sizes, int n_in,
                              void* d_out, int out_size, void* d_ws, size_t ws_size,
                              hipStream_t stream) {
    const float* feat = (const float*)d_in[0];
    const float* W1   = (const float*)d_in[1];
    const float* b1   = (const float*)d_in[2];
    const float* W2   = (const float*)d_in[3];
    const float* b2   = (const float*)d_in[4];
    const float* W3   = (const float*)d_in[5];
    const float* b3   = (const float*)d_in[6];
    const float* W4   = (const float*)d_in[7];
    const float* b4   = (const float*)d_in[8];
    const int* label  = (const int*)d_in[9];

    const int N = in_sizes[0] / (CCH * HH * WW);   // = 2

    float* pooled = (float*)d_ws;                   // [3][N][512]
    float* h1     = pooled + (size_t)3 * N * 512;   // [3][N][256]
    float* h2     = h1     + (size_t)3 * N * 256;   // [3][N][256]
    float* h3     = h2     + (size_t)3 * N * 256;   // [3][N][128]
    int*   cnt    = (int*)(h3 + (size_t)3 * N * 128); // 8 ints

    stats_kernel<<<N * CCH, 512, 0, stream>>>(feat, pooled, cnt, N);

    mlp_mega<<<481, 256, 0, stream>>>(pooled, W1, b1, W2, b2, W3, b3, W4, b4,
                                      label, h1, h2, h3, cnt, (float*)d_out);
}